// Round 5
// baseline (180.003 us; speedup 1.0000x reference)
//
#include <hip/hip_runtime.h>
#include <stdint.h>

typedef __attribute__((ext_vector_type(8))) short short8;
typedef __attribute__((ext_vector_type(8))) unsigned short u16x8;
typedef __attribute__((ext_vector_type(4))) float f32x4;

#define DEV __device__ __forceinline__

DEV float bf2f(unsigned short v) {
    union { unsigned int u; float f; } c;
    c.u = ((unsigned int)v) << 16;
    return c.f;
}
DEV unsigned short f2bf(float f) {
    union { float f; unsigned int u; } c;
    c.f = f;
    unsigned int x = c.u;
    x += 0x7fffu + ((x >> 16) & 1u);   // round-to-nearest-even
    return (unsigned short)(x >> 16);
}

// ---------------------------------------------------------------------------
// K1: embedding gather + FM first/second order + write deep (bf16, K=2496)
// block (64,4): lane = d (0..63), 4 batch rows per block.
// ---------------------------------------------------------------------------
__global__ __launch_bounds__(256) void embed_fm(
    const int* __restrict__ cat, const float* __restrict__ cont,
    const float* __restrict__ bias,
    const float* __restrict__ t1c, const float* __restrict__ t2c,
    const float* __restrict__ t1x, const float* __restrict__ t2x,
    unsigned short* __restrict__ deep, float* __restrict__ fm)
{
    __shared__ unsigned short rowbuf[4][2496];   // 19.5 KiB
    const int ty = threadIdx.y;
    const int row = blockIdx.x * 4 + ty;
    const int d = threadIdx.x;
    const int* crow = cat + row * 26;
    const float* xrow = cont + row * 13;

    float s = 0.f, ss = 0.f;
    #pragma unroll
    for (int f = 0; f < 26; ++f) {
        int idx = crow[f];                                  // wave-uniform load
        float e = t2c[((size_t)f * 100000 + idx) * 64 + d]; // coalesced 256B row
        s += e; ss += e * e;
        rowbuf[ty][f * 64 + d] = f2bf(e);
    }
    #pragma unroll
    for (int f = 0; f < 13; ++f) {
        float x = xrow[f];
        float e = t2x[f * 64 + d] * x;
        s += e; ss += e * e;
        rowbuf[ty][(26 + f) * 64 + d] = f2bf(e);
    }

    float val = 0.5f * (s * s - ss);
    if (d < 26) val += t1c[(size_t)d * 100000 + crow[d]];
    if (d < 13) val += t1x[d] * xrow[d];
    #pragma unroll
    for (int off = 32; off; off >>= 1) val += __shfl_xor(val, off);
    if (d == 0) fm[row] = bias[0] + val;

    __syncthreads();
    // cooperative coalesced store: 4 rows x 2496 = 9984 elems = 1248 x 8-elem chunks
    const int tid = ty * 64 + d;
    const unsigned short* src = &rowbuf[0][0];
    unsigned short* dst = deep + (size_t)(blockIdx.x * 4) * 2496;
    #pragma unroll
    for (int it = 0; it < 5; ++it) {
        int off = it * 2048 + tid * 8;
        if (off < 9984)
            *(u16x8*)(dst + off) = *(const u16x8*)(src + off);
    }
}

// ---------------------------------------------------------------------------
// Merged transpose + fp32->bf16 cast for W1 (2496x1024 -> 1024x2496) and
// W2 (1024x512 -> 512x1024). block (32,8); one flattened grid.
// ---------------------------------------------------------------------------
__global__ __launch_bounds__(256) void transpose_both(
    const float* __restrict__ W1, unsigned short* __restrict__ w1t,
    const float* __restrict__ W2, unsigned short* __restrict__ w2t)
{
    __shared__ float tile[32][33];
    int b = blockIdx.x;
    const float* in; unsigned short* out; int R, C, bx, by;
    if (b < 2496) { in = W1; out = w1t; R = 2496; C = 1024; bx = b % 32; by = b / 32; }
    else { b -= 2496; in = W2; out = w2t; R = 1024; C = 512; bx = b % 16; by = b / 16; }
    int c0 = bx * 32, r0 = by * 32;
    int tx = threadIdx.x, ty = threadIdx.y;
    #pragma unroll
    for (int i = 0; i < 4; ++i)
        tile[ty + i * 8][tx] = in[(size_t)(r0 + ty + i * 8) * C + c0 + tx];
    __syncthreads();
    #pragma unroll
    for (int i = 0; i < 4; ++i)
        out[(size_t)(c0 + ty + i * 8) * R + r0 + tx] = f2bf(tile[tx][ty + i * 8]);
}

// ---------------------------------------------------------------------------
// GEMM1: 256x256-tile 8-wave bf16 GEMM, TRUE counted-vmcnt pipeline (raw
// s_barrier, no compiler vmcnt(0) drain), LDS XOR swizzle, setprio, fused
// per-column sum/sumsq epilogue.  C[M,N] = A[M,K]*Bt[N,K]^T, K%64==0, NT>=3.
//
// Per tile t (buf cb = t&1), 3 barriers:
//   pA: ds_read A-mh0(8) + B-all(8); 32 MFMA Q(0,*)   [consumes ALL B regs]
//   bar1  (every wave's B ds_reads completed -- lgkm wait precedes its MFMAs)
//   pB: issue STAGE_B(t+2)->buf[cb].B (safe: B consumed); ds_read A-mh1(8);
//       32 MFMA Q(1,*)                                [consumes ALL A regs]
//   bar2  (A consumed)
//   pC: issue STAGE_A(t+2)->buf[cb].A; s_waitcnt vmcnt(8) -- drains tile
//       t+1's 8 loads, leaves t+2's 8 in flight; bar3.
// ---------------------------------------------------------------------------
__global__ __launch_bounds__(512, 2) void gemm256(
    const unsigned short* __restrict__ A,
    const unsigned short* __restrict__ Bt,
    unsigned short* __restrict__ C,
    float* __restrict__ sums, float* __restrict__ sqs,
    int M, int N, int K)
{
    __shared__ unsigned short lds[2][32768];   // [buf][A:0..16384 | B:16384..32768]
    const int tid = threadIdx.x;
    const int lane = tid & 63, wid = tid >> 6;
    const int wrow = wid >> 2, wcol = wid & 3;
    const int nbn = N >> 8;
    const int bm = blockIdx.x / nbn, bn = blockIdx.x % nbn;
    const int NT = K >> 6;

    // staging: pre-swizzled global source, linear LDS dest (guide rule #21)
    const int srow = tid >> 3;
    const int skc  = (tid & 7) ^ (srow & 7);
    const unsigned short* Asrc = A + (size_t)(bm * 256 + srow) * K + skc * 8;
    const unsigned short* Bsrc = Bt + (size_t)(bn * 256 + srow) * K + skc * 8;

    #define STAGE_A(kt, b)                                                        \
        _Pragma("unroll")                                                         \
        for (int i_ = 0; i_ < 4; ++i_)                                            \
            __builtin_amdgcn_global_load_lds(                                     \
                (const __attribute__((address_space(1))) void*)(Asrc + (size_t)(i_ * 64) * K + (kt)), \
                (__attribute__((address_space(3))) void*)(&lds[b][tid * 8 + i_ * 4096]), 16, 0, 0);
    #define STAGE_B(kt, b)                                                        \
        _Pragma("unroll")                                                         \
        for (int i_ = 0; i_ < 4; ++i_)                                            \
            __builtin_amdgcn_global_load_lds(                                     \
                (const __attribute__((address_space(1))) void*)(Bsrc + (size_t)(i_ * 64) * K + (kt)), \
                (__attribute__((address_space(3))) void*)(&lds[b][16384 + tid * 8 + i_ * 4096]), 16, 0, 0);

    // fragment read offsets (swizzled; 2 lanes/bank-quad -> conflict-free)
    const int l15 = lane & 15, l7 = lane & 7, lhi = lane >> 4;
    const int xo0 = 8 * (lhi ^ l7);
    const int xo1 = 8 * ((lhi + 4) ^ l7);
    const int aRow = wrow * 128 + l15;
    const int bRow = wcol * 64 + l15;

    f32x4 acc[8][4];
    #pragma unroll
    for (int m = 0; m < 8; ++m)
        #pragma unroll
        for (int n = 0; n < 4; ++n) acc[m][n] = (f32x4){0.f, 0.f, 0.f, 0.f};

    STAGE_A(0, 0); STAGE_B(0, 0);
    STAGE_A(64, 1); STAGE_B(64, 1);
    asm volatile("s_waitcnt vmcnt(8)" ::: "memory");
    __builtin_amdgcn_s_barrier();

    for (int t = 0; t < NT; ++t) {
        const int cb = t & 1;
        const unsigned short* base = &lds[cb][0];
        const int ktp = (t + 2) << 6;
        const bool pf = (t + 2) < NT;

        short8 a[4][2], bfr[4][2];
        // ---- pA: read A-mh0 + all B; MFMA Q(0,*) x32 ----
        #pragma unroll
        for (int mf = 0; mf < 4; ++mf) {
            a[mf][0] = *(const short8*)(base + (aRow + mf * 16) * 64 + xo0);
            a[mf][1] = *(const short8*)(base + (aRow + mf * 16) * 64 + xo1);
        }
        #pragma unroll
        for (int nf = 0; nf < 4; ++nf) {
            bfr[nf][0] = *(const short8*)(base + 16384 + (bRow + nf * 16) * 64 + xo0);
            bfr[nf][1] = *(const short8*)(base + 16384 + (bRow + nf * 16) * 64 + xo1);
        }
        __builtin_amdgcn_s_setprio(1);
        #pragma unroll
        for (int mf = 0; mf < 4; ++mf)
            #pragma unroll
            for (int nf = 0; nf < 4; ++nf)
                #pragma unroll
                for (int kk = 0; kk < 2; ++kk)
                    acc[mf][nf] = __builtin_amdgcn_mfma_f32_16x16x32_bf16(
                        a[mf][kk], bfr[nf][kk], acc[mf][nf], 0, 0, 0);
        __builtin_amdgcn_s_setprio(0);
        __builtin_amdgcn_s_barrier();   // bar1: all waves consumed B region

        // ---- pB: stage B(t+2); read A-mh1; MFMA Q(1,*) x32 ----
        if (pf) { STAGE_B(ktp, cb); }
        #pragma unroll
        for (int mf = 0; mf < 4; ++mf) {
            a[mf][0] = *(const short8*)(base + (aRow + (mf + 4) * 16) * 64 + xo0);
            a[mf][1] = *(const short8*)(base + (aRow + (mf + 4) * 16) * 64 + xo1);
        }
        __builtin_amdgcn_s_setprio(1);
        #pragma unroll
        for (int mf = 0; mf < 4; ++mf)
            #pragma unroll
            for (int nf = 0; nf < 4; ++nf)
                #pragma unroll
                for (int kk = 0; kk < 2; ++kk)
                    acc[4 + mf][nf] = __builtin_amdgcn_mfma_f32_16x16x32_bf16(
                        a[mf][kk], bfr[nf][kk], acc[4 + mf][nf], 0, 0, 0);
        __builtin_amdgcn_s_setprio(0);
        __builtin_amdgcn_s_barrier();   // bar2: all waves consumed A region

        // ---- pC: stage A(t+2); counted wait for tile t+1; barrier ----
        if (t + 1 < NT) {
            if (pf) {
                STAGE_A(ktp, cb);
                asm volatile("s_waitcnt vmcnt(8)" ::: "memory");
            } else {
                asm volatile("s_waitcnt vmcnt(0)" ::: "memory");
            }
            __builtin_amdgcn_s_barrier();   // bar3: tile t+1 data visible to all
        }
    }

    // ---- epilogue: C write (bf16) + fused column sum/sumsq ----
    const int row0 = bm * 256 + wrow * 128 + lhi * 4;
    const int col0 = bn * 256 + wcol * 64 + l15;
    #pragma unroll
    for (int mf = 0; mf < 8; ++mf)
        #pragma unroll
        for (int nf = 0; nf < 4; ++nf)
            #pragma unroll
            for (int r = 0; r < 4; ++r)
                C[(size_t)(row0 + mf * 16 + r) * N + col0 + nf * 16] = f2bf(acc[mf][nf][r]);

    float s[4] = {0, 0, 0, 0}, q[4] = {0, 0, 0, 0};
    #pragma unroll
    for (int mf = 0; mf < 8; ++mf)
        #pragma unroll
        for (int nf = 0; nf < 4; ++nf)
            #pragma unroll
            for (int r = 0; r < 4; ++r) {
                float v = acc[mf][nf][r];
                s[nf] += v; q[nf] += v * v;
            }
    #pragma unroll
    for (int nf = 0; nf < 4; ++nf) {
        s[nf] += __shfl_xor(s[nf], 16); s[nf] += __shfl_xor(s[nf], 32);
        q[nf] += __shfl_xor(q[nf], 16); q[nf] += __shfl_xor(q[nf], 32);
    }
    if (lane < 16) {
        #pragma unroll
        for (int nf = 0; nf < 4; ++nf) {
            atomicAdd(&sums[col0 + nf * 16], s[nf]);
            atomicAdd(&sqs[col0 + nf * 16], q[nf]);
        }
    }
    #undef STAGE_A
    #undef STAGE_B
}

// ---------------------------------------------------------------------------
// GEMM2 fused: A = relu(BN1(z1)) computed in-flight during reg-staged A
// (BN1 coefficients derived from raw sums/sqs once per block into LDS);
// B via global_load_lds; fused column stats for BN2.  128x128 tile, m97 loop.
// ---------------------------------------------------------------------------
__global__ __launch_bounds__(256) void gemm2_fused(
    const unsigned short* __restrict__ z1,
    const unsigned short* __restrict__ Bt,
    unsigned short* __restrict__ C,
    const float* __restrict__ sums1, const float* __restrict__ sqs1,
    const float* __restrict__ g1, const float* __restrict__ be1,
    float* __restrict__ sums2, float* __restrict__ sqs2,
    int M, int N, int K, float invB)
{
    __shared__ unsigned short As[128 * 64];
    __shared__ unsigned short Bs[128 * 64];
    __shared__ float a1s[1024], b1s[1024];
    const int nbn = N >> 7;
    const int bm = blockIdx.x / nbn;
    const int bn = blockIdx.x % nbn;
    const int tid = threadIdx.x;
    const int lane = tid & 63;
    const int wave = tid >> 6;
    const int wr = (wave >> 1) << 6;
    const int wc = (wave & 1) << 6;

    // BN1 coefficients (folds bn_finalize): once per block
    for (int c = tid; c < K; c += 256) {
        float mu = sums1[c] * invB;
        float var = sqs1[c] * invB - mu * mu;
        float sc = g1[c] * rsqrtf(var + 1e-5f);
        a1s[c] = sc;
        b1s[c] = be1[c] - mu * sc;
    }
    __syncthreads();

    const int arow = bm * 128 + (tid >> 3);
    const int acol = (tid & 7) * 8;
    const unsigned short* Bb = Bt + (size_t)(bn * 128 + (tid >> 3)) * K + acol;
    unsigned short* Bsl = &Bs[tid * 8];

    f32x4 acc[4][4];
    #pragma unroll
    for (int m = 0; m < 4; ++m)
        #pragma unroll
        for (int n = 0; n < 4; ++n) acc[m][n] = (f32x4){0.f, 0.f, 0.f, 0.f};

    const int frow = lane & 15;
    const int fk = (lane >> 4) * 8;

    for (int kt = 0; kt < K; kt += 64) {
        // B staging: async global->LDS
        #pragma unroll
        for (int i = 0; i < 4; ++i)
            __builtin_amdgcn_global_load_lds(
                (const __attribute__((address_space(1))) void*)(Bb + (size_t)(i * 32) * K + kt),
                (__attribute__((address_space(3))) void*)(Bsl + i * 2048), 16, 0, 0);
        // A staging: reg-staged z1 with BN1+ReLU applied in flight
        u16x8 va[4];
        #pragma unroll
        for (int i = 0; i < 4; ++i)
            va[i] = *(const u16x8*)&z1[(size_t)(arow + i * 32) * K + kt + acol];
        const int c0 = kt + acol;
        float4 av0 = *(const float4*)&a1s[c0];
        float4 av1 = *(const float4*)&a1s[c0 + 4];
        float4 bv0 = *(const float4*)&b1s[c0];
        float4 bv1 = *(const float4*)&b1s[c0 + 4];
        float av[8] = {av0.x, av0.y, av0.z, av0.w, av1.x, av1.y, av1.z, av1.w};
        float bv[8] = {bv0.x, bv0.y, bv0.z, bv0.w, bv1.x, bv1.y, bv1.z, bv1.w};
        #pragma unroll
        for (int i = 0; i < 4; ++i) {
            short8 w;
            #pragma unroll
            for (int j = 0; j < 8; ++j)
                w[j] = (short)f2bf(fmaxf(av[j] * bf2f(va[i][j]) + bv[j], 0.f));
            *(short8*)&As[tid * 8 + i * 2048] = w;
        }
        __syncthreads();
        #pragma unroll
        for (int kk = 0; kk < 64; kk += 32) {
            short8 af[4], bfv[4];
            #pragma unroll
            for (int m = 0; m < 4; ++m)
                af[m] = *(const short8*)&As[(wr + m * 16 + frow) * 64 + kk + fk];
            #pragma unroll
            for (int n = 0; n < 4; ++n)
                bfv[n] = *(const short8*)&Bs[(wc + n * 16 + frow) * 64 + kk + fk];
            #pragma unroll
            for (int m = 0; m < 4; ++m)
                #pragma unroll
                for (int n = 0; n < 4; ++n)
                    acc[m][n] = __builtin_amdgcn_mfma_f32_16x16x32_bf16(
                        af[m], bfv[n], acc[m][n], 0, 0, 0);
        }
        __syncthreads();
    }

    const int row0 = bm * 128 + wr + (lane >> 4) * 4;
    const int col0 = bn * 128 + wc + (lane & 15);
    #pragma unroll
    for (int m = 0; m < 4; ++m)
        #pragma unroll
        for (int n = 0; n < 4; ++n)
            #pragma unroll
            for (int r = 0; r < 4; ++r)
                C[(size_t)(row0 + m * 16 + r) * N + col0 + n * 16] = f2bf(acc[m][n][r]);

    float s[4] = {0, 0, 0, 0}, q[4] = {0, 0, 0, 0};
    #pragma unroll
    for (int m = 0; m < 4; ++m)
        #pragma unroll
        for (int n = 0; n < 4; ++n)
            #pragma unroll
            for (int r = 0; r < 4; ++r) {
                float v = acc[m][n][r];
                s[n] += v; q[n] += v * v;
            }
    #pragma unroll
    for (int n = 0; n < 4; ++n) {
        s[n] += __shfl_xor(s[n], 16); s[n] += __shfl_xor(s[n], 32);
        q[n] += __shfl_xor(q[n], 16); q[n] += __shfl_xor(q[n], 32);
    }
    if (lane < 16) {
        #pragma unroll
        for (int n = 0; n < 4; ++n) {
            atomicAdd(&sums2[col0 + n * 16], s[n]);
            atomicAdd(&sqs2[col0 + n * 16], q[n]);
        }
    }
}

// ---------------------------------------------------------------------------
// Final: BN2 (coeffs from raw stats, folded) + ReLU + dot(W3) + b3 + fm
// -> sigmoid -> [1-p, p].  block (64,4): one wave per row.
// ---------------------------------------------------------------------------
__global__ __launch_bounds__(256) void final_k(
    const unsigned short* __restrict__ z2,
    const float* __restrict__ sums2, const float* __restrict__ sqs2,
    const float* __restrict__ g2, const float* __restrict__ be2,
    const float* __restrict__ W3, const float* __restrict__ b3,
    const float* __restrict__ fm, float* __restrict__ out, float invB)
{
    int row = blockIdx.x * 4 + threadIdx.y;
    int lane = threadIdx.x;
    int c = lane * 8;
    u16x8 u = *(const u16x8*)&z2[(size_t)row * 512 + c];
    float dot = 0.f;
    #pragma unroll
    for (int j = 0; j < 8; ++j) {
        float mu = sums2[c + j] * invB;
        float var = sqs2[c + j] * invB - mu * mu;
        float a = g2[c + j] * rsqrtf(var + 1e-5f);
        float b = be2[c + j] - mu * a;
        float x = a * bf2f(u[j]) + b;
        dot += fmaxf(x, 0.f) * W3[c + j];
    }
    #pragma unroll
    for (int off = 32; off; off >>= 1) dot += __shfl_xor(dot, off);
    if (lane == 0) {
        float logit = fm[row] + dot + b3[0];
        float p = 1.f / (1.f + expf(-logit));
        out[row * 2 + 0] = 1.f - p;
        out[row * 2 + 1] = p;
    }
}

// ---------------------------------------------------------------------------
extern "C" void kernel_launch(void* const* d_in, const int* in_sizes, int n_in,
                              void* d_out, int out_size, void* d_ws, size_t ws_size,
                              hipStream_t stream)
{
    const int*   cat  = (const int*)d_in[0];
    const float* cont = (const float*)d_in[1];
    const float* bias = (const float*)d_in[2];
    const float* t1c  = (const float*)d_in[3];
    const float* t2c  = (const float*)d_in[4];
    const float* t1x  = (const float*)d_in[5];
    const float* t2x  = (const float*)d_in[6];
    const float* W1   = (const float*)d_in[7];
    // d_in[8] = b1: cancels under training-mode BN
    const float* g1   = (const float*)d_in[9];
    const float* be1  = (const float*)d_in[10];
    const float* W2   = (const float*)d_in[11];
    // d_in[12] = b2: cancels
    const float* g2   = (const float*)d_in[13];
    const float* be2  = (const float*)d_in[14];
    const float* W3   = (const float*)d_in[15];
    const float* b3   = (const float*)d_in[16];
    float* out = (float*)d_out;

    const int B = 16384, K1 = 2496, H1 = 1024, H2 = 512;

    uint8_t* p = (uint8_t*)d_ws;
    auto carve = [&](size_t bytes) {
        uint8_t* r = p;
        p += (bytes + 255) & ~(size_t)255;
        return r;
    };
    unsigned short* deep = (unsigned short*)carve((size_t)B * K1 * 2);   // 81.8 MB
    unsigned short* w1t  = (unsigned short*)carve((size_t)H1 * K1 * 2);
    unsigned short* w2t  = (unsigned short*)carve((size_t)H2 * H1 * 2);
    unsigned short* z1   = (unsigned short*)carve((size_t)B * H1 * 2);
    unsigned short* z2   = (unsigned short*)carve((size_t)B * H2 * 2);
    float* fm    = (float*)carve((size_t)B * 4);
    float* stats = (float*)carve((size_t)(H1 * 2 + H2 * 2) * 4);
    float* sums1 = stats, *sqs1 = stats + H1, *sums2 = stats + 2 * H1, *sqs2 = stats + 2 * H1 + H2;

    hipMemsetAsync(stats, 0, (size_t)(H1 * 2 + H2 * 2) * 4, stream);

    // W1 + W2 transpose/cast in one launch: 2496 + 512 = 3008 blocks
    transpose_both<<<3008, dim3(32, 8), 0, stream>>>(W1, w1t, W2, w2t);

    embed_fm<<<B / 4, dim3(64, 4), 0, stream>>>(cat, cont, bias, t1c, t2c, t1x, t2x, deep, fm);

    // GEMM1: 256^2 tile, true counted-vmcnt pipeline, fused BN1 stats
    gemm256<<<(B / 256) * (H1 / 256), 512, 0, stream>>>(deep, w1t, z1, sums1, sqs1, B, H1, K1);

    // GEMM2: BN1-apply+ReLU fused into A staging, fused BN2 stats
    gemm2_fused<<<(B / 128) * (H2 / 128), 256, 0, stream>>>(
        z1, w2t, z2, sums1, sqs1, g1, be1, sums2, sqs2, B, H2, H1, 1.f / B);

    final_k<<<B / 4, dim3(64, 4), 0, stream>>>(z2, sums2, sqs2, g2, be2, W3, b3, fm, out, 1.f / B);
}

// Round 6
// 156.898 us; speedup vs baseline: 1.1473x; 1.1473x over previous
//
#include <hip/hip_runtime.h>
#include <stdint.h>

typedef __attribute__((ext_vector_type(8))) short short8;
typedef __attribute__((ext_vector_type(8))) unsigned short u16x8;
typedef __attribute__((ext_vector_type(4))) float f32x4;

#define DEV __device__ __forceinline__

DEV float bf2f(unsigned short v) {
    union { unsigned int u; float f; } c;
    c.u = ((unsigned int)v) << 16;
    return c.f;
}
DEV unsigned short f2bf(float f) {
    union { float f; unsigned int u; } c;
    c.f = f;
    unsigned int x = c.u;
    x += 0x7fffu + ((x >> 16) & 1u);   // round-to-nearest-even
    return (unsigned short)(x >> 16);
}

// K layout: cols 0..1663 = 26 cat embeddings (26x64); cols 1664..1676 = raw
// cont features (rank-13 folding); cols 1677..1727 = zero.  KP = 1728 = 27*64.
#define KCAT 1664
#define KP   1728

// ---------------------------------------------------------------------------
// K1: embedding gather + FM first/second order + write deep (bf16, KP cols)
// block (64,4): lane = d (0..63), 4 batch rows per block.
// ---------------------------------------------------------------------------
__global__ __launch_bounds__(256) void embed_fm(
    const int* __restrict__ cat, const float* __restrict__ cont,
    const float* __restrict__ bias,
    const float* __restrict__ t1c, const float* __restrict__ t2c,
    const float* __restrict__ t1x, const float* __restrict__ t2x,
    unsigned short* __restrict__ deep, float* __restrict__ fm)
{
    __shared__ unsigned short rowbuf[4][KP];   // 13.5 KiB
    const int ty = threadIdx.y;
    const int row = blockIdx.x * 4 + ty;
    const int d = threadIdx.x;
    const int* crow = cat + row * 26;
    const float* xrow = cont + row * 13;

    float s = 0.f, ss = 0.f;
    #pragma unroll
    for (int f = 0; f < 26; ++f) {
        int idx = crow[f];                                  // wave-uniform load
        float e = t2c[((size_t)f * 100000 + idx) * 64 + d]; // coalesced 256B row
        s += e; ss += e * e;
        rowbuf[ty][f * 64 + d] = f2bf(e);
    }
    #pragma unroll
    for (int f = 0; f < 13; ++f) {
        float x = xrow[f];
        float e = t2x[f * 64 + d] * x;
        s += e; ss += e * e;
    }
    // rank-13 cont tile: raw cont features, zero-padded to 64
    rowbuf[ty][KCAT + d] = (d < 13) ? f2bf(xrow[d]) : (unsigned short)0;

    float val = 0.5f * (s * s - ss);
    if (d < 26) val += t1c[(size_t)d * 100000 + crow[d]];
    if (d < 13) val += t1x[d] * xrow[d];
    #pragma unroll
    for (int off = 32; off; off >>= 1) val += __shfl_xor(val, off);
    if (d == 0) fm[row] = bias[0] + val;

    __syncthreads();
    // cooperative coalesced store: 4 rows x 1728 = 6912 elems
    const int tid = ty * 64 + d;
    const unsigned short* src = &rowbuf[0][0];
    unsigned short* dst = deep + (size_t)(blockIdx.x * 4) * KP;
    #pragma unroll
    for (int it = 0; it < 4; ++it) {
        int off = it * 2048 + tid * 8;
        if (off < 4 * KP)
            *(u16x8*)(dst + off) = *(const u16x8*)(src + off);
    }
}

// ---------------------------------------------------------------------------
// Merged transpose + fp32->bf16 cast: W1 rows 0..1663 -> w1t[1024][KP] cols
// 0..1663;  W2 (1024x512) -> w2t[512][1024]. block (32,8).
// ---------------------------------------------------------------------------
__global__ __launch_bounds__(256) void transpose_both(
    const float* __restrict__ W1, unsigned short* __restrict__ w1t,
    const float* __restrict__ W2, unsigned short* __restrict__ w2t)
{
    __shared__ float tile[32][33];
    int b = blockIdx.x;
    const float* in; unsigned short* out; int C, KO, bx, by;
    if (b < 1664) { in = W1; out = w1t; C = 1024; KO = KP; bx = b & 31; by = b >> 5; }
    else { b -= 1664; in = W2; out = w2t; C = 512; KO = 1024; bx = b & 15; by = b >> 4; }
    int c0 = bx * 32, r0 = by * 32;
    int tx = threadIdx.x, ty = threadIdx.y;
    #pragma unroll
    for (int i = 0; i < 4; ++i)
        tile[ty + i * 8][tx] = in[(size_t)(r0 + ty + i * 8) * C + c0 + tx];
    __syncthreads();
    #pragma unroll
    for (int i = 0; i < 4; ++i)
        out[(size_t)(c0 + ty + i * 8) * KO + r0 + tx] = f2bf(tile[tx][ty + i * 8]);
}

// ---------------------------------------------------------------------------
// Fill w1t cols 1664..1727:  P[n,f] = sum_d t2x[f,d] * W1[1664+64f+d, n]
// (rank-13 cont folding), zero for f>=13.  grid (4,13), block 256: thread = n.
// ---------------------------------------------------------------------------
__global__ __launch_bounds__(256) void cont_w1(
    const float* __restrict__ W1, const float* __restrict__ t2x,
    unsigned short* __restrict__ w1t)
{
    int n = blockIdx.x * 256 + threadIdx.x;   // 0..1023
    int f = blockIdx.y;                        // 0..12
    float s = 0.f;
    #pragma unroll 8
    for (int d = 0; d < 64; ++d)
        s += W1[(size_t)(KCAT + f * 64 + d) * 1024 + n] * t2x[f * 64 + d];
    w1t[(size_t)n * KP + KCAT + f] = f2bf(s);
    if (f == 0) {
        for (int j = KCAT + 13; j < KP; ++j)
            w1t[(size_t)n * KP + j] = 0;
    }
}

// ---------------------------------------------------------------------------
// GEMM1: 256x256-tile 8-wave bf16 GEMM, counted-vmcnt pipeline (raw s_barrier),
// LDS XOR swizzle, setprio, XCD-chunked block swizzle, fused column stats.
// C[M,N] = A[M,K]*Bt[N,K]^T, K%64==0, NT>=3, gridDim.x%8==0.
// ---------------------------------------------------------------------------
__global__ __launch_bounds__(512, 2) void gemm256(
    const unsigned short* __restrict__ A,
    const unsigned short* __restrict__ Bt,
    unsigned short* __restrict__ C,
    float* __restrict__ sums, float* __restrict__ sqs,
    int M, int N, int K)
{
    __shared__ unsigned short lds[2][32768];   // [buf][A:0..16384 | B:16384..32768]
    const int tid = threadIdx.x;
    const int lane = tid & 63, wid = tid >> 6;
    const int wrow = wid >> 2, wcol = wid & 3;
    const int nbn = N >> 8;
    const int cpx = gridDim.x >> 3;
    const int swzb = (blockIdx.x & 7) * cpx + (blockIdx.x >> 3);
    const int bm = swzb / nbn, bn = swzb % nbn;
    const int NT = K >> 6;

    const int srow = tid >> 3;
    const int skc  = (tid & 7) ^ (srow & 7);
    const unsigned short* Asrc = A + (size_t)(bm * 256 + srow) * K + skc * 8;
    const unsigned short* Bsrc = Bt + (size_t)(bn * 256 + srow) * K + skc * 8;

    #define STAGE_A(kt, b)                                                        \
        _Pragma("unroll")                                                         \
        for (int i_ = 0; i_ < 4; ++i_)                                            \
            __builtin_amdgcn_global_load_lds(                                     \
                (const __attribute__((address_space(1))) void*)(Asrc + (size_t)(i_ * 64) * K + (kt)), \
                (__attribute__((address_space(3))) void*)(&lds[b][tid * 8 + i_ * 4096]), 16, 0, 0);
    #define STAGE_B(kt, b)                                                        \
        _Pragma("unroll")                                                         \
        for (int i_ = 0; i_ < 4; ++i_)                                            \
            __builtin_amdgcn_global_load_lds(                                     \
                (const __attribute__((address_space(1))) void*)(Bsrc + (size_t)(i_ * 64) * K + (kt)), \
                (__attribute__((address_space(3))) void*)(&lds[b][16384 + tid * 8 + i_ * 4096]), 16, 0, 0);

    const int l15 = lane & 15, l7 = lane & 7, lhi = lane >> 4;
    const int xo0 = 8 * (lhi ^ l7);
    const int xo1 = 8 * ((lhi + 4) ^ l7);
    const int aRow = wrow * 128 + l15;
    const int bRow = wcol * 64 + l15;

    f32x4 acc[8][4];
    #pragma unroll
    for (int m = 0; m < 8; ++m)
        #pragma unroll
        for (int n = 0; n < 4; ++n) acc[m][n] = (f32x4){0.f, 0.f, 0.f, 0.f};

    STAGE_A(0, 0); STAGE_B(0, 0);
    STAGE_A(64, 1); STAGE_B(64, 1);
    asm volatile("s_waitcnt vmcnt(8)" ::: "memory");
    __builtin_amdgcn_s_barrier();

    for (int t = 0; t < NT; ++t) {
        const int cb = t & 1;
        const unsigned short* base = &lds[cb][0];
        const int ktp = (t + 2) << 6;
        const bool pf = (t + 2) < NT;

        short8 a[4][2], bfr[4][2];
        // ---- pA: read A-mh0 + all B; MFMA Q(0,*) x32 ----
        #pragma unroll
        for (int mf = 0; mf < 4; ++mf) {
            a[mf][0] = *(const short8*)(base + (aRow + mf * 16) * 64 + xo0);
            a[mf][1] = *(const short8*)(base + (aRow + mf * 16) * 64 + xo1);
        }
        #pragma unroll
        for (int nf = 0; nf < 4; ++nf) {
            bfr[nf][0] = *(const short8*)(base + 16384 + (bRow + nf * 16) * 64 + xo0);
            bfr[nf][1] = *(const short8*)(base + 16384 + (bRow + nf * 16) * 64 + xo1);
        }
        __builtin_amdgcn_s_setprio(1);
        #pragma unroll
        for (int mf = 0; mf < 4; ++mf)
            #pragma unroll
            for (int nf = 0; nf < 4; ++nf)
                #pragma unroll
                for (int kk = 0; kk < 2; ++kk)
                    acc[mf][nf] = __builtin_amdgcn_mfma_f32_16x16x32_bf16(
                        a[mf][kk], bfr[nf][kk], acc[mf][nf], 0, 0, 0);
        __builtin_amdgcn_s_setprio(0);
        __builtin_amdgcn_s_barrier();   // bar1: all waves consumed B region

        // ---- pB: stage B(t+2); read A-mh1; MFMA Q(1,*) x32 ----
        if (pf) { STAGE_B(ktp, cb); }
        #pragma unroll
        for (int mf = 0; mf < 4; ++mf) {
            a[mf][0] = *(const short8*)(base + (aRow + (mf + 4) * 16) * 64 + xo0);
            a[mf][1] = *(const short8*)(base + (aRow + (mf + 4) * 16) * 64 + xo1);
        }
        __builtin_amdgcn_s_setprio(1);
        #pragma unroll
        for (int mf = 0; mf < 4; ++mf)
            #pragma unroll
            for (int nf = 0; nf < 4; ++nf)
                #pragma unroll
                for (int kk = 0; kk < 2; ++kk)
                    acc[4 + mf][nf] = __builtin_amdgcn_mfma_f32_16x16x32_bf16(
                        a[mf][kk], bfr[nf][kk], acc[4 + mf][nf], 0, 0, 0);
        __builtin_amdgcn_s_setprio(0);
        __builtin_amdgcn_s_barrier();   // bar2: all waves consumed A region

        // ---- pC: stage A(t+2); counted wait for tile t+1; barrier ----
        if (t + 1 < NT) {
            if (pf) {
                STAGE_A(ktp, cb);
                asm volatile("s_waitcnt vmcnt(8)" ::: "memory");
            } else {
                asm volatile("s_waitcnt vmcnt(0)" ::: "memory");
            }
            __builtin_amdgcn_s_barrier();   // bar3: tile t+1 data visible
        }
    }

    // ---- epilogue: C write (bf16) + fused column sum/sumsq ----
    const int row0 = bm * 256 + wrow * 128 + lhi * 4;
    const int col0 = bn * 256 + wcol * 64 + l15;
    #pragma unroll
    for (int mf = 0; mf < 8; ++mf)
        #pragma unroll
        for (int nf = 0; nf < 4; ++nf)
            #pragma unroll
            for (int r = 0; r < 4; ++r)
                C[(size_t)(row0 + mf * 16 + r) * N + col0 + nf * 16] = f2bf(acc[mf][nf][r]);

    float s[4] = {0, 0, 0, 0}, q[4] = {0, 0, 0, 0};
    #pragma unroll
    for (int mf = 0; mf < 8; ++mf)
        #pragma unroll
        for (int nf = 0; nf < 4; ++nf)
            #pragma unroll
            for (int r = 0; r < 4; ++r) {
                float v = acc[mf][nf][r];
                s[nf] += v; q[nf] += v * v;
            }
    #pragma unroll
    for (int nf = 0; nf < 4; ++nf) {
        s[nf] += __shfl_xor(s[nf], 16); s[nf] += __shfl_xor(s[nf], 32);
        q[nf] += __shfl_xor(q[nf], 16); q[nf] += __shfl_xor(q[nf], 32);
    }
    if (lane < 16) {
        #pragma unroll
        for (int nf = 0; nf < 4; ++nf) {
            atomicAdd(&sums[col0 + nf * 16], s[nf]);
            atomicAdd(&sqs[col0 + nf * 16], q[nf]);
        }
    }
    #undef STAGE_A
    #undef STAGE_B
}

// BN1 coefficients once (removes per-block rsqrt redundancy in gemm2)
__global__ void bn1_coeff(const float* __restrict__ sums1, const float* __restrict__ sqs1,
                          const float* __restrict__ g1, const float* __restrict__ be1,
                          float* __restrict__ a1g, float* __restrict__ b1g, float invB)
{
    int c = blockIdx.x * 256 + threadIdx.x;
    float mu = sums1[c] * invB;
    float var = sqs1[c] * invB - mu * mu;
    float sc = g1[c] * rsqrtf(var + 1e-5f);
    a1g[c] = sc;
    b1g[c] = be1[c] - mu * sc;
}

// ---------------------------------------------------------------------------
// GEMM2: A = relu(BN1(z1)) reg-staged+transformed in flight (prefetched one
// tile ahead, T14), B double-buffered via global_load_lds staged one tile
// ahead with counted vmcnt(4), raw barriers, XOR-swizzled As/Bs, setprio,
// fused BN2 column stats.  128x128 tile, 4 waves, K%64==0, NT>=2.
// ---------------------------------------------------------------------------
__global__ __launch_bounds__(256) void gemm2_fused(
    const unsigned short* __restrict__ z1,
    const unsigned short* __restrict__ Bt,
    unsigned short* __restrict__ C,
    const float* __restrict__ a1g, const float* __restrict__ b1g,
    float* __restrict__ sums2, float* __restrict__ sqs2,
    int M, int N, int K)
{
    __shared__ unsigned short As[128 * 64];
    __shared__ unsigned short Bs[2][128 * 64];
    __shared__ float a1s[1024], b1s[1024];
    const int tid = threadIdx.x;
    const int lane = tid & 63;
    const int wave = tid >> 6;
    const int nbn = N >> 7;
    const int cpx = gridDim.x >> 3;
    const int swzb = (blockIdx.x & 7) * cpx + (blockIdx.x >> 3);
    const int bm = swzb / nbn, bn = swzb % nbn;
    const int NT = K >> 6;
    const int wr = (wave >> 1) << 6;
    const int wc = (wave & 1) << 6;

    for (int c = tid; c < K; c += 256) { a1s[c] = a1g[c]; b1s[c] = b1g[c]; }
    __syncthreads();   // coeffs visible; no async loads in flight yet

    const int srow = tid >> 3;               // 0..31
    const int sca  = (tid & 7) ^ (srow & 7); // swizzled chunk (write & B-src)
    const int acol = (tid & 7) * 8;
    const unsigned short* Asrc = z1 + (size_t)(bm * 128 + srow) * K + acol;
    const unsigned short* Bsrc = Bt + (size_t)(bn * 128 + srow) * K + sca * 8;

    #define STAGE_B2(kt, b)                                                     \
        _Pragma("unroll")                                                       \
        for (int i_ = 0; i_ < 4; ++i_)                                          \
            __builtin_amdgcn_global_load_lds(                                   \
                (const __attribute__((address_space(1))) void*)(Bsrc + (size_t)(i_ * 32) * K + (kt)), \
                (__attribute__((address_space(3))) void*)(&Bs[b][tid * 8 + i_ * 2048]), 16, 0, 0);

    const int l15 = lane & 15, l7 = lane & 7, lhi = lane >> 4;
    const int xo0 = 8 * (lhi ^ l7);
    const int xo1 = 8 * ((lhi + 4) ^ l7);

    f32x4 acc[4][4];
    #pragma unroll
    for (int m = 0; m < 4; ++m)
        #pragma unroll
        for (int n = 0; n < 4; ++n) acc[m][n] = (f32x4){0.f, 0.f, 0.f, 0.f};

    // prologue: B(0) staged, A(0) reg loads issued
    STAGE_B2(0, 0);
    u16x8 va[4];
    #pragma unroll
    for (int i = 0; i < 4; ++i)
        va[i] = *(const u16x8*)(Asrc + (size_t)(i * 32) * K);

    for (int t = 0; t < NT; ++t) {
        const int cur = t & 1;
        const int kt = t << 6;
        const bool pf = (t + 1) < NT;
        if (pf) { STAGE_B2(kt + 64, cur ^ 1); }
        // outstanding (oldest first): B(t)x4, A(t)x4, [B(t+1)x4]
        if (pf) asm volatile("s_waitcnt vmcnt(4)" ::: "memory");   // B(t)+A(t) done
        else    asm volatile("s_waitcnt vmcnt(0)" ::: "memory");

        // BN1 + ReLU transform -> swizzled ds_write
        {
            const int c0 = kt + acol;
            float av[8], bv[8];
            #pragma unroll
            for (int j = 0; j < 8; ++j) { av[j] = a1s[c0 + j]; bv[j] = b1s[c0 + j]; }
            #pragma unroll
            for (int i = 0; i < 4; ++i) {
                short8 w;
                #pragma unroll
                for (int j = 0; j < 8; ++j)
                    w[j] = (short)f2bf(fmaxf(av[j] * bf2f(va[i][j]) + bv[j], 0.f));
                *(short8*)&As[(srow + i * 32) * 64 + 8 * sca] = w;
            }
        }
        // prefetch A(t+1) regs (latency hides under compute)
        if (pf) {
            #pragma unroll
            for (int i = 0; i < 4; ++i)
                va[i] = *(const u16x8*)(Asrc + (size_t)(i * 32) * K + kt + 64);
        }
        asm volatile("s_waitcnt lgkmcnt(0)" ::: "memory");   // ds_writes done
        __builtin_amdgcn_s_barrier();
        __builtin_amdgcn_sched_barrier(0);

        // compute: 16 ds_read_b128 + 32 MFMA
        const unsigned short* bb = &Bs[cur][0];
        short8 af[4][2], bfv[4][2];
        #pragma unroll
        for (int m = 0; m < 4; ++m) {
            af[m][0] = *(const short8*)&As[(wr + m * 16 + l15) * 64 + xo0];
            af[m][1] = *(const short8*)&As[(wr + m * 16 + l15) * 64 + xo1];
        }
        #pragma unroll
        for (int n = 0; n < 4; ++n) {
            bfv[n][0] = *(const short8*)(bb + (wc + n * 16 + l15) * 64 + xo0);
            bfv[n][1] = *(const short8*)(bb + (wc + n * 16 + l15) * 64 + xo1);
        }
        __builtin_amdgcn_s_setprio(1);
        #pragma unroll
        for (int m = 0; m < 4; ++m)
            #pragma unroll
            for (int n = 0; n < 4; ++n)
                #pragma unroll
                for (int kk = 0; kk < 2; ++kk)
                    acc[m][n] = __builtin_amdgcn_mfma_f32_16x16x32_bf16(
                        af[m][kk], bfv[n][kk], acc[m][n], 0, 0, 0);
        __builtin_amdgcn_s_setprio(0);
        __builtin_amdgcn_s_barrier();   // As / Bs[cur] consumed by all waves
    }

    const int row0 = bm * 128 + wr + lhi * 4;
    const int col0 = bn * 128 + wc + l15;
    #pragma unroll
    for (int m = 0; m < 4; ++m)
        #pragma unroll
        for (int n = 0; n < 4; ++n)
            #pragma unroll
            for (int r = 0; r < 4; ++r)
                C[(size_t)(row0 + m * 16 + r) * N + col0 + n * 16] = f2bf(acc[m][n][r]);

    float s[4] = {0, 0, 0, 0}, q[4] = {0, 0, 0, 0};
    #pragma unroll
    for (int m = 0; m < 4; ++m)
        #pragma unroll
        for (int n = 0; n < 4; ++n)
            #pragma unroll
            for (int r = 0; r < 4; ++r) {
                float v = acc[m][n][r];
                s[n] += v; q[n] += v * v;
            }
    #pragma unroll
    for (int n = 0; n < 4; ++n) {
        s[n] += __shfl_xor(s[n], 16); s[n] += __shfl_xor(s[n], 32);
        q[n] += __shfl_xor(q[n], 16); q[n] += __shfl_xor(q[n], 32);
    }
    if (lane < 16) {
        #pragma unroll
        for (int n = 0; n < 4; ++n) {
            atomicAdd(&sums2[col0 + n * 16], s[n]);
            atomicAdd(&sqs2[col0 + n * 16], q[n]);
        }
    }
    #undef STAGE_B2
}

// ---------------------------------------------------------------------------
// Final: BN2 (coeffs from raw stats, folded) + ReLU + dot(W3) + b3 + fm
// -> sigmoid -> [1-p, p].  block (64,4): one wave per row.
// ---------------------------------------------------------------------------
__global__ __launch_bounds__(256) void final_k(
    const unsigned short* __restrict__ z2,
    const float* __restrict__ sums2, const float* __restrict__ sqs2,
    const float* __restrict__ g2, const float* __restrict__ be2,
    const float* __restrict__ W3, const float* __restrict__ b3,
    const float* __restrict__ fm, float* __restrict__ out, float invB)
{
    int row = blockIdx.x * 4 + threadIdx.y;
    int lane = threadIdx.x;
    int c = lane * 8;
    u16x8 u = *(const u16x8*)&z2[(size_t)row * 512 + c];
    float dot = 0.f;
    #pragma unroll
    for (int j = 0; j < 8; ++j) {
        float mu = sums2[c + j] * invB;
        float var = sqs2[c + j] * invB - mu * mu;
        float a = g2[c + j] * rsqrtf(var + 1e-5f);
        float b = be2[c + j] - mu * a;
        float x = a * bf2f(u[j]) + b;
        dot += fmaxf(x, 0.f) * W3[c + j];
    }
    #pragma unroll
    for (int off = 32; off; off >>= 1) dot += __shfl_xor(dot, off);
    if (lane == 0) {
        float logit = fm[row] + dot + b3[0];
        float p = 1.f / (1.f + expf(-logit));
        out[row * 2 + 0] = 1.f - p;
        out[row * 2 + 1] = p;
    }
}

// ---------------------------------------------------------------------------
extern "C" void kernel_launch(void* const* d_in, const int* in_sizes, int n_in,
                              void* d_out, int out_size, void* d_ws, size_t ws_size,
                              hipStream_t stream)
{
    const int*   cat  = (const int*)d_in[0];
    const float* cont = (const float*)d_in[1];
    const float* bias = (const float*)d_in[2];
    const float* t1c  = (const float*)d_in[3];
    const float* t2c  = (const float*)d_in[4];
    const float* t1x  = (const float*)d_in[5];
    const float* t2x  = (const float*)d_in[6];
    const float* W1   = (const float*)d_in[7];
    // d_in[8] = b1: cancels under training-mode BN
    const float* g1   = (const float*)d_in[9];
    const float* be1  = (const float*)d_in[10];
    const float* W2   = (const float*)d_in[11];
    // d_in[12] = b2: cancels
    const float* g2   = (const float*)d_in[13];
    const float* be2  = (const float*)d_in[14];
    const float* W3   = (const float*)d_in[15];
    const float* b3   = (const float*)d_in[16];
    float* out = (float*)d_out;

    const int B = 16384, H1 = 1024, H2 = 512;

    uint8_t* p = (uint8_t*)d_ws;
    auto carve = [&](size_t bytes) {
        uint8_t* r = p;
        p += (bytes + 255) & ~(size_t)255;
        return r;
    };
    unsigned short* deep = (unsigned short*)carve((size_t)B * KP * 2);   // 56.6 MB
    unsigned short* w1t  = (unsigned short*)carve((size_t)H1 * KP * 2);
    unsigned short* w2t  = (unsigned short*)carve((size_t)H2 * H1 * 2);
    unsigned short* z1   = (unsigned short*)carve((size_t)B * H1 * 2);
    unsigned short* z2   = (unsigned short*)carve((size_t)B * H2 * 2);
    float* fm    = (float*)carve((size_t)B * 4);
    float* stats = (float*)carve((size_t)(H1 * 2 + H2 * 2) * 4);
    float* sums1 = stats, *sqs1 = stats + H1, *sums2 = stats + 2 * H1, *sqs2 = stats + 2 * H1 + H2;
    float* a1g = (float*)carve(H1 * 4);
    float* b1g = (float*)carve(H1 * 4);

    hipMemsetAsync(stats, 0, (size_t)(H1 * 2 + H2 * 2) * 4, stream);

    // weight prep: transpose W1-top/W2 + rank-13 cont fold into w1t tail
    transpose_both<<<1664 + 512, dim3(32, 8), 0, stream>>>(W1, w1t, W2, w2t);
    cont_w1<<<dim3(4, 13), 256, 0, stream>>>(W1, t2x, w1t);

    embed_fm<<<B / 4, dim3(64, 4), 0, stream>>>(cat, cont, bias, t1c, t2c, t1x, t2x, deep, fm);

    // GEMM1: K = 1728 (26 cat tiles + 1 cont tile), fused BN1 stats
    gemm256<<<(B / 256) * (H1 / 256), 512, 0, stream>>>(deep, w1t, z1, sums1, sqs1, B, H1, KP);

    bn1_coeff<<<H1 / 256, 256, 0, stream>>>(sums1, sqs1, g1, be1, a1g, b1g, 1.f / B);

    // GEMM2: BN1-apply+ReLU fused into pipelined A staging, fused BN2 stats
    gemm2_fused<<<(B / 128) * (H2 / 128), 256, 0, stream>>>(
        z1, w2t, z2, a1g, b1g, sums2, sqs2, B, H2, H1);

    final_k<<<B / 4, dim3(64, 4), 0, stream>>>(z2, sums2, sqs2, g2, be2, W3, b3, fm, out, 1.f / B);
}